// Round 14
// baseline (135.662 us; speedup 1.0000x reference)
//
#include <hip/hip_runtime.h>

typedef __bf16 bf16x8 __attribute__((ext_vector_type(8)));
typedef float f32x4 __attribute__((ext_vector_type(4)));

#define MFMA_BF16(a, b, c) __builtin_amdgcn_mfma_f32_16x16x32_bf16((a), (b), (c), 0, 0, 0)

#define C1 0.18033688f  // 0.125 * log2(e)

static __device__ __forceinline__ unsigned short f2bf(float f) {
    unsigned int u = __float_as_uint(f);
    unsigned int r = (u + 0x7fffu + ((u >> 16) & 1u)) >> 16;
    return (unsigned short)r;
}
static __device__ __forceinline__ float bf2f(unsigned short us) {
    return __uint_as_float(((unsigned int)us) << 16);
}
static __device__ __forceinline__ float exp2_hw(float x) {
    float r;
    asm("v_exp_f32 %0, %1" : "=v"(r) : "v"(x));
    return r;
}
// pack two f32 -> bf16 pair, round-half-up (3 ops); low half = a, high = b
static __device__ __forceinline__ unsigned pack_rh(float a, float b) {
    return __byte_perm(__float_as_uint(a) + 0x8000u, __float_as_uint(b) + 0x8000u, 0x7632);
}
// async 16B global -> LDS (DMA, no VGPR round-trip)
static __device__ __forceinline__ void gload16(const void* g, void* l) {
    __builtin_amdgcn_global_load_lds(
        (const __attribute__((address_space(1))) unsigned int*)g,
        (__attribute__((address_space(3))) unsigned int*)l, 16, 0, 0);
}

// ---------------------------------------------------------------------------
// GEMM v4 (3-kernel pipeline; conversion fully fused): C = A @ W^T + bias.
// K=256, BM=64, BN=NSUB*64 per block, 4 waves. NSUB sub-tiles share one
// A-fragment load (f32 A: float4+pack_rh converted ONCE — kills r12's 12x
// re-read; bf16 A: direct 16B loads). B double-buffered 2x8KB, 4*NSUB
// statically-unrolled phases with the r13-verified stage-ahead schedule;
// bf16 B = gload16 DMA, f32 B = reg-staged pack into the same swizzled
// layout. Per-block dtype sniff on W (wave-uniform ballot). Epilogue:
// plain sub-tiles direct-store; V sub-tiles (ct>=512, QKV) via LDS
// transpose to TILED Vt [bh][kt][64 d][128 k] with block-uniform barriers.
// gemm2 = <false,1> — byte-identical to r13's measured path.
// ---------------------------------------------------------------------------
template <bool QKV, int NSUB>
__global__ __launch_bounds__(256) void gemm_kernel(
    const void* __restrict__ Av, const void* __restrict__ Wv,
    const void* __restrict__ biasv, unsigned short* __restrict__ Cb,
    float* __restrict__ Cf, unsigned short* __restrict__ Vt, int Nout) {
    constexpr int K = 256;
    constexpr int NP = NSUB * 4;
    __shared__ __align__(16) char sm[16384];  // B0|B1 8KB each; V-transpose reuse

    const int tid = threadIdx.x;
    const int lane = tid & 63;
    const int wv = tid >> 6;
    const int m16 = lane & 15;
    const int quad = lane >> 4;
    const int bm = blockIdx.x * 64;
    const int bn0 = blockIdx.y * (NSUB * 64);

    // dtype sniff (wave-uniform; weights/bias/x share dtype)
    int cnt = 0;
    {
        const unsigned short* sw = (const unsigned short*)Wv;
#pragma unroll
        for (int i = 0; i < 4; i++) {
            const int e = (sw[i * 64 + lane] >> 7) & 0xFF;
            cnt += __popcll(__ballot(e >= 195));
        }
    }
    const bool f32 = (cnt >= 8);

    // B staging offsets (64 rows x 8 chunks of 16B per buffer, XOR-swizzled)
    int bgo[2], blo[2], brow[2], bchk[2];
#pragma unroll
    for (int i = 0; i < 2; i++) {
        const int c = wv * 128 + i * 64 + lane;
        const int r = c >> 3, g = (c & 7) ^ (r & 7);
        bgo[i] = r * (K * 2) + g * 16;
        blo[i] = c * 16;
        brow[i] = r;
        bchk[i] = g;
    }
    int bro[4][2];
#pragma unroll
    for (int t = 0; t < 4; t++)
#pragma unroll
        for (int ks = 0; ks < 2; ks++) {
            const int row = t * 16 + m16;
            bro[t][ks] = row * 64 + ((4 * ks + quad) ^ (m16 & 7)) * 8;
        }

    const float* Wf = (const float*)Wv;

    // stage one B sub-tile (sub,kb) into buffer buf
    auto stageB = [&](int sub, int kb, int buf) {
        if (f32) {
#pragma unroll
            for (int i = 0; i < 2; i++) {
                const float* src =
                    Wf + (size_t)(bn0 + sub * 64 + brow[i]) * K + kb * 64 + bchk[i] * 8;
                const float4 u0 = *(const float4*)src;
                const float4 u1 = *(const float4*)(src + 4);
                uint4 p;
                p.x = pack_rh(u0.x, u0.y);
                p.y = pack_rh(u0.z, u0.w);
                p.z = pack_rh(u1.x, u1.y);
                p.w = pack_rh(u1.z, u1.w);
                *(uint4*)(sm + buf * 8192 + blo[i]) = p;
            }
        } else {
            const char* bgs = (const char*)Wv + (size_t)(bn0 + sub * 64) * K * 2;
#pragma unroll
            for (int i = 0; i < 2; i++)
                gload16(bgs + kb * 128 + bgo[i], sm + buf * 8192 + blo[i]);
        }
    };

    // prologue: B(0,0) -> buffer 0; ALL A fragments -> regs (loaded once,
    // shared by every sub-tile; f32 converted in-register once)
    stageB(0, 0, 0);
    bf16x8 a[4][2];
    if (QKV && f32) {
        const float* Af = (const float*)Av + (size_t)(bm + wv * 16 + m16) * K + quad * 8;
#pragma unroll
        for (int kb = 0; kb < 4; kb++)
#pragma unroll
            for (int ks = 0; ks < 2; ks++) {
                const float4 u0 = *(const float4*)(Af + kb * 64 + ks * 32);
                const float4 u1 = *(const float4*)(Af + kb * 64 + ks * 32 + 4);
                uint4 p;
                p.x = pack_rh(u0.x, u0.y);
                p.y = pack_rh(u0.z, u0.w);
                p.z = pack_rh(u1.x, u1.y);
                p.w = pack_rh(u1.z, u1.w);
                a[kb][ks] = *(const bf16x8*)&p;
            }
    } else {
        const unsigned short* ap =
            (const unsigned short*)Av + (size_t)(bm + wv * 16 + m16) * K + quad * 8;
#pragma unroll
        for (int kb = 0; kb < 4; kb++)
#pragma unroll
            for (int ks = 0; ks < 2; ks++)
                a[kb][ks] = *(const bf16x8*)(ap + kb * 64 + ks * 32);
    }

    // 4*NSUB phases, double-buffered, staged one phase ahead (r13 schedule)
    f32x4 acc[NSUB][4] = {};
#pragma unroll
    for (int p = 0; p < NP; p++) {
        __syncthreads();  // drains B staging issued a full compute phase ago
        const int cur = p & 1;
        if (p + 1 < NP) stageB((p + 1) >> 2, (p + 1) & 3, cur ^ 1);
        const unsigned short* Blds = (const unsigned short*)(sm + cur * 8192);
        const int sub = p >> 2, kb = p & 3;
#pragma unroll
        for (int ks = 0; ks < 2; ks++)
#pragma unroll
            for (int t = 0; t < 4; t++) {
                const bf16x8 b = *(const bf16x8*)(Blds + bro[t][ks]);
                acc[sub][t] = MFMA_BF16(a[kb][ks], b, acc[sub][t]);
            }
    }

    const float* bf_ = (const float*)biasv;
    const unsigned short* bh_ = (const unsigned short*)biasv;
    const int row0 = bm + wv * 16 + quad * 4;

    // plain epilogue for non-V sub-tiles
#pragma unroll
    for (int sub = 0; sub < NSUB; sub++) {
        const int ct = bn0 + sub * 64;
        if (QKV && ct >= 512) continue;  // V handled below
#pragma unroll
        for (int t = 0; t < 4; t++) {
            const int col = ct + t * 16 + m16;
            const float bv = f32 ? bf_[col] : bf2f(bh_[col]);
            float v[4];
#pragma unroll
            for (int r = 0; r < 4; r++) v[r] = acc[sub][t][r] + bv;
            if (QKV) {
                const float sc = (col < 256) ? C1 : 1.0f;
#pragma unroll
                for (int r = 0; r < 4; r++)
                    Cb[(size_t)(row0 + r) * 768 + col] = f2bf(v[r] * sc);
            } else {
                if (f32) {
#pragma unroll
                    for (int r = 0; r < 4; r++) Cf[(size_t)(row0 + r) * Nout + col] = v[r];
                } else {
#pragma unroll
                    for (int r = 0; r < 4; r++)
                        Cb[(size_t)(row0 + r) * Nout + col] = f2bf(v[r]);
                }
            }
        }
    }

    // V sub-tiles: transpose via LDS -> TILED Vt[bh][kt][64 d][128 k]
    if (QKV) {
#pragma unroll
        for (int sub = 0; sub < NSUB; sub++) {
            const int ct = bn0 + sub * 64;
            if (ct < 512) continue;  // block-uniform condition
            __syncthreads();  // LDS free (B reads / previous tr done)
            unsigned short* tr = (unsigned short*)sm;  // [64 d][72 pad] bf16
            const int lr = wv * 16 + quad * 4;
#pragma unroll
            for (int t = 0; t < 4; t++) {
                const int col = ct + t * 16 + m16;
                const float bv = f32 ? bf_[col] : bf2f(bh_[col]);
                uint2 w;
                w.x = pack_rh(acc[sub][t][0] + bv, acc[sub][t][1] + bv);
                w.y = pack_rh(acc[sub][t][2] + bv, acc[sub][t][3] + bv);
                *(uint2*)&tr[(t * 16 + m16) * 72 + lr] = w;
            }
            __syncthreads();
            // 4 threads per d-row, 16 elements (2 x uint4) each
            const int d = tid >> 2;
            const int ch = (tid & 3) * 16;
            const uint4 o4a = *(const uint4*)&tr[d * 72 + ch];
            const uint4 o4b = *(const uint4*)&tr[d * 72 + ch + 8];
            const int hh = (ct - 512) >> 6;
            const int bb = bm >> 12, n0 = bm & 4095;
            const int nn = n0 + ch;                   // start n of this 16-chunk
            const int kt = nn >> 7, koff = nn & 127;  // k-tile, k within tile
            unsigned short* vdst =
                &Vt[(size_t)(((bb * 4 + hh) * 32 + kt) * 64 + d) * 128 + koff];
            *(uint4*)(vdst) = o4a;
            *(uint4*)(vdst + 8) = o4b;
        }
    }
}

// ---------------------------------------------------------------------------
// Flash attention v7 (VERIFIED 47.4-51.3 µs): barrier-free, wave-private
// slabs, tiled Vt, counted vmcnt, zero-shuffle PV + one-tile software-
// pipeline rotation (QK^T(t+1) before exp(t)/PV(t)).
// ---------------------------------------------------------------------------
#define ZERO_S(S)                                                     \
    do {                                                              \
        _Pragma("unroll") for (int mb = 0; mb < 2; mb++)              \
            _Pragma("unroll") for (int j = 0; j < 4; j++)             \
                S[mb][j] = (f32x4){0.f, 0.f, 0.f, 0.f};               \
    } while (0)

#define QKT(S, KBASE)                                                          \
    do {                                                                       \
        const unsigned short* Kb_ = (const unsigned short*)(KBASE);            \
        __builtin_amdgcn_s_setprio(1);                                         \
        _Pragma("unroll") for (int mb = 0; mb < 2; mb++)                       \
            _Pragma("unroll") for (int ks = 0; ks < 2; ks++) {                 \
                const bf16x8 ka_ = *(const bf16x8*)(Kb_ + kro[mb][ks]);        \
                _Pragma("unroll") for (int j = 0; j < 4; j++)                  \
                    S[mb][j] = MFMA_BF16(ka_, qf[j][ks], S[mb][j]);            \
            }                                                                  \
        __builtin_amdgcn_s_setprio(0);                                         \
    } while (0)

#define EXPP(S, PA)                                                            \
    do {                                                                       \
        _Pragma("unroll") for (int j = 0; j < 4; j++) {                        \
            const float e0 = exp2_hw(S[0][j][0]);                              \
            const float e1 = exp2_hw(S[0][j][1]);                              \
            const float e2 = exp2_hw(S[0][j][2]);                              \
            const float e3 = exp2_hw(S[0][j][3]);                              \
            const float e4 = exp2_hw(S[1][j][0]);                              \
            const float e5 = exp2_hw(S[1][j][1]);                              \
            const float e6 = exp2_hw(S[1][j][2]);                              \
            const float e7 = exp2_hw(S[1][j][3]);                              \
            uint4 pw_;                                                         \
            pw_.x = pack_rh(e0, e1);                                           \
            pw_.y = pack_rh(e2, e3);                                           \
            pw_.z = pack_rh(e4, e5);                                           \
            pw_.w = pack_rh(e6, e7);                                           \
            PA[j] = *(const bf16x8*)&pw_;                                      \
        }                                                                      \
    } while (0)

#define PVACC(PA, VBASE)                                                       \
    do {                                                                       \
        const unsigned short* Vb_ = (const unsigned short*)(VBASE);            \
        __builtin_amdgcn_s_setprio(1);                                         \
        _Pragma("unroll") for (int j = 0; j < 4; j++)                          \
            o1[j] = MFMA_BF16(PA[j], ones, o1[j]);                             \
        _Pragma("unroll") for (int t = 0; t < 4; t++) {                        \
            const uint2 va_ = *(const uint2*)(Vb_ + vroA[t]);                  \
            const uint2 vc_ = *(const uint2*)(Vb_ + (vroA[t] ^ 16));           \
            uint4 vv_;                                                         \
            vv_.x = va_.x;                                                     \
            vv_.y = va_.y;                                                     \
            vv_.z = vc_.x;                                                     \
            vv_.w = vc_.y;                                                     \
            const bf16x8 vb_ = *(const bf16x8*)&vv_;                           \
            _Pragma("unroll") for (int j = 0; j < 4; j++)                      \
                o[j][t] = MFMA_BF16(PA[j], vb_, o[j][t]);                      \
        }                                                                      \
        __builtin_amdgcn_s_setprio(0);                                         \
    } while (0)

#define GLK(DST)                                                               \
    {                                                                          \
        _Pragma("unroll") for (int i = 0; i < 4; i++)                          \
            gload16(kgn + kgo[i], (DST) + klo[i]);                             \
        kgn += 196608;                                                         \
    }
#define GLV(DST)                                                               \
    {                                                                          \
        _Pragma("unroll") for (int i = 0; i < 4; i++)                          \
            gload16(vgn + vgo[i], (DST) + vlo[i]);                             \
        vgn += 16384;                                                          \
    }

__global__ __launch_bounds__(256, 2) void attn_kernel(
    const unsigned short* __restrict__ qkv, const unsigned short* __restrict__ Vt,
    unsigned short* __restrict__ attn, int iters) {
    const int N = 4096, C3 = 768;
    __shared__ __align__(16) char sm[65536];  // [4 wv][2 buf][4KB K] | +32768 same for V

    const int tid = threadIdx.x;
    const int lane = tid & 63;
    const int wv = tid >> 6;
    const int m16 = lane & 15;
    const int quad = lane >> 4;

    const int bh = blockIdx.x & 7;  // XCD-locality: same bh -> same XCD
    const int qt = blockIdx.x >> 3;
    const int b = bh >> 2, h = bh & 3;

    // Q fragments (pre-scaled by C1 in gemm1): qf[j-block][kstep]
    bf16x8 qf[4][2];
#pragma unroll
    for (int j = 0; j < 4; j++)
#pragma unroll
        for (int ks = 0; ks < 2; ks++)
            qf[j][ks] = *(const bf16x8*)(qkv + ((size_t)b * N + qt * 64 + j * 16 + m16) * C3 +
                                         h * 64 + ks * 32 + quad * 8);

    // all-ones B operand (bf16 1.0 splat) for the l-row trick
    uint4 ones_u;
    ones_u.x = ones_u.y = ones_u.z = ones_u.w = 0x3F803F80u;
    const bf16x8 ones = *(const bf16x8*)&ones_u;

    // wave-private staging offsets (identical to v6).
    int kgo[4], vgo[4], klo[4], vlo[4];
#pragma unroll
    for (int i = 0; i < 4; i++) {
        const int c = i * 64 + lane;
        const int r = c >> 3, g = (c & 7) ^ (r & 7);
        kgo[i] = (wv * 32 + r) * 1536 + g * 16;
        klo[i] = c * 16;
        const int d = c >> 2, js = c & 3, jg = js ^ ((d >> 2) & 3);
        vgo[i] = d * 256 + wv * 64 + jg * 16;
        vlo[i] = c * 16;
    }
    int kro[2][2];
#pragma unroll
    for (int mb = 0; mb < 2; mb++)
#pragma unroll
        for (int ks = 0; ks < 2; ks++) {
            const int row = mb * 16 + m16;
            kro[mb][ks] = row * 64 + ((4 * ks + quad) ^ (m16 & 7)) * 8;
        }
    int vroA[4];
#pragma unroll
    for (int t = 0; t < 4; t++) {
        const int d = t * 16 + m16;
        const int c0 = (quad >> 1) ^ ((d >> 2) & 3);
        vroA[t] = d * 32 + c0 * 8 + (quad & 1) * 4;
    }

    char* Kreg0 = sm + wv * 8192;           // buf0; buf1 = +4096
    char* Vreg0 = sm + 32768 + wv * 8192;   // buf0; buf1 = +4096

    const char* kgp = (const char*)(qkv + (size_t)b * N * C3 + 256 + h * 64);
    const char* vgp = (const char*)(Vt + (size_t)bh * 262144);  // 32 tiles x 8192

    // prologue: tiles 0 and 1 fully issued (16 loads; qf's 8 loads precede)
#pragma unroll
    for (int i = 0; i < 4; i++) gload16(kgp + kgo[i], Kreg0 + klo[i]);
#pragma unroll
    for (int i = 0; i < 4; i++) gload16(vgp + vgo[i], Vreg0 + vlo[i]);
#pragma unroll
    for (int i = 0; i < 4; i++) gload16(kgp + 196608 + kgo[i], Kreg0 + 4096 + klo[i]);
#pragma unroll
    for (int i = 0; i < 4; i++) gload16(vgp + 16384 + vgo[i], Vreg0 + 4096 + vlo[i]);
    const char* kgn = kgp + 2 * 196608;  // next K to stage: tile 2
    const char* vgn = vgp + 2 * 16384;   // next V to stage: tile 2

    f32x4 o[4][4] = {};
    f32x4 o1[4] = {};  // l accumulator: o1[j][r] = l[q = j*16 + quad*4 + r]
    f32x4 sA[2][4], sB[2][4];
    bf16x8 pa[4];

    // preamble: S(0) (vmcnt(12) also drains the 8 qf loads + K(0))
    asm volatile("s_waitcnt vmcnt(12)" ::: "memory");
    ZERO_S(sA);
    QKT(sA, Kreg0);

    // 15 unrolled body-pairs = bodies 0..29 (tiles 0..29 consumed)
    for (int t2 = 0; t2 < 15; ++t2) {
        // body t = 2*t2 (even; cur=buf0): QK^T(t+1) || exp/PV(t)
        asm volatile("s_waitcnt vmcnt(4)" ::: "memory");  // V(t), K(t+1) landed
        GLK(Kreg0);                                       // K(t+2) -> buf0.K (K(t) free)
        ZERO_S(sB);
        QKT(sB, Kreg0 + 4096);                            // tile t+1 from buf1.K
        EXPP(sA, pa);                                     // independent of QKT above
        PVACC(pa, Vreg0);                                 // tile t from buf0.V
        asm volatile("s_waitcnt lgkmcnt(0)" ::: "memory");  // V reads retired
        GLV(Vreg0);                                       // V(t+2) -> buf0.V

        // body t+1 (odd; cur=buf1)
        asm volatile("s_waitcnt vmcnt(4)" ::: "memory");  // V(t+1), K(t+2) landed
        GLK(Kreg0 + 4096);                                // K(t+3) -> buf1.K
        ZERO_S(sA);
        QKT(sA, Kreg0);                                   // tile t+2 from buf0.K
        EXPP(sB, pa);
        PVACC(pa, Vreg0 + 4096);                          // tile t+1 from buf1.V
        asm volatile("s_waitcnt lgkmcnt(0)" ::: "memory");
        GLV(Vreg0 + 4096);                                // V(t+3) -> buf1.V
    }
    // body 30 (even; no prefetch): QK^T(31) || exp/PV(30)
    asm volatile("s_waitcnt vmcnt(4)" ::: "memory");      // V(30), K(31) landed
    ZERO_S(sB);
    QKT(sB, Kreg0 + 4096);
    EXPP(sA, pa);
    PVACC(pa, Vreg0);
    // body 31 (final): exp/PV(31)
    asm volatile("s_waitcnt vmcnt(0)" ::: "memory");      // V(31) landed
    EXPP(sB, pa);
    PVACC(pa, Vreg0 + 4096);

    // epilogue: cross-wave O/l reduction via LDS (first barrier of the kernel)
    __syncthreads();
    float* Ored = (float*)sm;            // [4 wv][16 q][64 d] slices per j
    float* lsum = (float*)(sm + 16384);  // [4 wv][64 q]
    if (m16 == 0) {
#pragma unroll
        for (int j = 0; j < 4; j++)
#pragma unroll
            for (int r = 0; r < 4; r++)
                lsum[wv * 64 + j * 16 + quad * 4 + r] = o1[j][r];
    }
    const int row = tid >> 4;
    const int col = (tid & 15) * 4;
#pragma unroll
    for (int j = 0; j < 4; j++) {
#pragma unroll
        for (int t = 0; t < 4; t++)
#pragma unroll
            for (int r = 0; r < 4; r++)
                Ored[(wv * 16 + quad * 4 + r) * 64 + t * 16 + m16] = o[j][t][r];
        __syncthreads();
        f32x4 sum = *(f32x4*)&Ored[row * 64 + col];
        sum += *(f32x4*)&Ored[1024 + row * 64 + col];
        sum += *(f32x4*)&Ored[2048 + row * 64 + col];
        sum += *(f32x4*)&Ored[3072 + row * 64 + col];
        const float lq = lsum[j * 16 + row] + lsum[64 + j * 16 + row] +
                         lsum[128 + j * 16 + row] + lsum[192 + j * 16 + row];
        const int n = qt * 64 + j * 16 + row;
        const float inv = 1.0f / lq;
        uint2 w;
        w.x = pack_rh(sum[0] * inv, sum[1] * inv);
        w.y = pack_rh(sum[2] * inv, sum[3] * inv);
        *(uint2*)&attn[((size_t)b * N + n) * 256 + h * 64 + col] = w;
        __syncthreads();
    }
}

// ---------------------------------------------------------------------------
extern "C" void kernel_launch(void* const* d_in, const int* in_sizes, int n_in,
                              void* d_out, int out_size, void* d_ws, size_t ws_size,
                              hipStream_t stream) {
    const int B = 2, N = 4096, H = 4;
    const int M = B * N;  // 8192

    char* wsb = (char*)d_ws;
    unsigned short* qkv_ws  = (unsigned short*)wsb;             // [8192][768] bf16
    unsigned short* Vt_ws   = qkv_ws + 6291456;                 // [8][32][64][128] tiled
    unsigned short* attn_ws = Vt_ws + 2097152;                  // [8192][256] bf16

    // 1) QKV projection, NSUB=3 (BN=192): fused x/W conversion, A loaded
    //    once per block (Q pre-scaled by C1; V transposed to tiled Vt)
    gemm_kernel<true, 3><<<dim3(M / 64, 4), 256, 0, stream>>>(
        d_in[0], d_in[1], d_in[2], qkv_ws, nullptr, Vt_ws, 768);

    // 2) flash attention v7
    attn_kernel<<<512, 256, 0, stream>>>(qkv_ws, Vt_ws, attn_ws, 32);

    // 3) output projection, NSUB=1 (r13's measured path; output dtype per sniff)
    gemm_kernel<false, 1><<<dim3(M / 64, 4), 256, 0, stream>>>(
        attn_ws, d_in[3], d_in[4], (unsigned short*)d_out, (float*)d_out, nullptr, 256);
}

// Round 15
// 131.474 us; speedup vs baseline: 1.0318x; 1.0318x over previous
//
#include <hip/hip_runtime.h>

typedef __bf16 bf16x8 __attribute__((ext_vector_type(8)));
typedef float f32x4 __attribute__((ext_vector_type(4)));

#define MFMA_BF16(a, b, c) __builtin_amdgcn_mfma_f32_16x16x32_bf16((a), (b), (c), 0, 0, 0)

#define C1 0.18033688f  // 0.125 * log2(e)

static __device__ __forceinline__ unsigned short f2bf(float f) {
    unsigned int u = __float_as_uint(f);
    unsigned int r = (u + 0x7fffu + ((u >> 16) & 1u)) >> 16;
    return (unsigned short)r;
}
static __device__ __forceinline__ float bf2f(unsigned short us) {
    return __uint_as_float(((unsigned int)us) << 16);
}
static __device__ __forceinline__ float exp2_hw(float x) {
    float r;
    asm("v_exp_f32 %0, %1" : "=v"(r) : "v"(x));
    return r;
}
// pack two f32 -> bf16 pair, round-half-up (3 ops); low half = a, high = b
static __device__ __forceinline__ unsigned pack_rh(float a, float b) {
    return __byte_perm(__float_as_uint(a) + 0x8000u, __float_as_uint(b) + 0x8000u, 0x7632);
}
// async 16B global -> LDS (DMA, no VGPR round-trip)
static __device__ __forceinline__ void gload16(const void* g, void* l) {
    __builtin_amdgcn_global_load_lds(
        (const __attribute__((address_space(1))) unsigned int*)g,
        (__attribute__((address_space(3))) unsigned int*)l, 16, 0, 0);
}

// ---------------------------------------------------------------------------
// Convert x only -> bf16 xb (weights are consumed in-place by the gemms).
// 1024 blocks x 256 thr x 8 elems. Per-block self-sniff of x's dtype.
// ---------------------------------------------------------------------------
__global__ __launch_bounds__(256) void convert_x_kernel(
    const void* __restrict__ x, unsigned short* __restrict__ xb) {
    const int lane = threadIdx.x & 63;
    int cnt = 0;
    {
        const unsigned short* sx = (const unsigned short*)x;
#pragma unroll
        for (int i = 0; i < 4; i++) {
            const int e = (sx[i * 64 + lane] >> 7) & 0xFF;
            cnt += __popcll(__ballot(e >= 195));
        }
    }
    const bool f32 = (cnt >= 8);
    const int base = blockIdx.x * 2048 + (int)threadIdx.x * 8;
    if (f32) {
        const float4 u0 = *(const float4*)((const float*)x + base);
        const float4 u1 = *(const float4*)((const float*)x + base + 4);
        uint4 p;
        p.x = pack_rh(u0.x, u0.y);
        p.y = pack_rh(u0.z, u0.w);
        p.z = pack_rh(u1.x, u1.y);
        p.w = pack_rh(u1.z, u1.w);
        *(uint4*)(xb + base) = p;
    } else {
        *(uint4*)(xb + base) = *(const uint4*)((const unsigned short*)x + base);
    }
}

// ---------------------------------------------------------------------------
// GEMM (r8 double-buffered structure + fused weight conversion):
// C = A @ W^T + bias. K=256, 64x64 tile/block, 4 waves. A is ALWAYS bf16
// (xb / attn_ws) -> direct 16B global loads, software-prefetched one kb
// ahead (r8's fastest measured path). B tile double-buffered 2x8KB: per-block
// dtype sniff on W (wave-uniform 4x __ballot over first 256 ushorts) — bf16
// path = gload16 DMA (byte-identical to r8); f32 path = reg-staged
// fp32->bf16 (pack_rh, identical rounding) into the SAME swizzled layout,
// same barrier schedule (syncthreads' lgkm drain covers ds_writes).
// QKV: cols<256 scaled by C1; >=512 (V) transposed via LDS to TILED
// Vt [bh][kt][64 d][128 k]. !QKV: output dtype per own sniff.
// ---------------------------------------------------------------------------
template <bool QKV>
__global__ __launch_bounds__(256) void gemm_kernel(
    const unsigned short* __restrict__ A, const void* __restrict__ Wv,
    const void* __restrict__ biasv, unsigned short* __restrict__ Cb,
    float* __restrict__ Cf, unsigned short* __restrict__ Vt, int Nout) {
    constexpr int K = 256;
    __shared__ __align__(16) char sm[16384];  // B0|B1 8KB each; V-transpose reuse

    const int tid = threadIdx.x;
    const int lane = tid & 63;
    const int wv = tid >> 6;
    const int m16 = lane & 15;
    const int quad = lane >> 4;
    const int bm = blockIdx.x * 64;
    const int bn = blockIdx.y * 64;

    // dtype sniff (wave-uniform; weights/bias share dtype with x)
    int cnt = 0;
    {
        const unsigned short* sw = (const unsigned short*)Wv;
#pragma unroll
        for (int i = 0; i < 4; i++) {
            const int e = (sw[i * 64 + lane] >> 7) & 0xFF;
            cnt += __popcll(__ballot(e >= 195));
        }
    }
    const bool f32 = (cnt >= 8);

    // B staging offsets (64 rows x 8 chunks of 16B per buffer, XOR-swizzled)
    int bgo[2], blo[2], brow[2], bchk[2];
#pragma unroll
    for (int i = 0; i < 2; i++) {
        const int c = wv * 128 + i * 64 + lane;
        const int r = c >> 3, g = (c & 7) ^ (r & 7);
        bgo[i] = r * (K * 2) + g * 16;
        blo[i] = c * 16;
        brow[i] = r;
        bchk[i] = g;
    }
    int bro[4][2];
#pragma unroll
    for (int t = 0; t < 4; t++)
#pragma unroll
        for (int ks = 0; ks < 2; ks++) {
            const int row = t * 16 + m16;
            bro[t][ks] = row * 64 + ((4 * ks + quad) ^ (m16 & 7)) * 8;
        }

    const char* bg = (const char*)Wv + (size_t)bn * K * 2;  // bf16 view
    const float* Wf = (const float*)Wv;
    const unsigned short* ap = A + (size_t)(bm + wv * 16 + m16) * K + quad * 8;

    // stage one B sub-tile (kb) into buffer buf
    auto stageB = [&](int kb, int buf) {
        if (f32) {
#pragma unroll
            for (int i = 0; i < 2; i++) {
                const float* src = Wf + (size_t)(bn + brow[i]) * K + kb * 64 + bchk[i] * 8;
                const float4 u0 = *(const float4*)src;
                const float4 u1 = *(const float4*)(src + 4);
                uint4 p;
                p.x = pack_rh(u0.x, u0.y);
                p.y = pack_rh(u0.z, u0.w);
                p.z = pack_rh(u1.x, u1.y);
                p.w = pack_rh(u1.z, u1.w);
                *(uint4*)(sm + buf * 8192 + blo[i]) = p;
            }
        } else {
#pragma unroll
            for (int i = 0; i < 2; i++)
                gload16(bg + kb * 128 + bgo[i], sm + buf * 8192 + blo[i]);
        }
    };

    // prologue: B tile 0 -> buffer 0; A frags for kb=0 -> regs
    stageB(0, 0);
    bf16x8 a0 = *(const bf16x8*)(ap);
    bf16x8 a1 = *(const bf16x8*)(ap + 32);

    f32x4 acc[4] = {};
#pragma unroll
    for (int kb = 0; kb < 4; kb++) {
        __syncthreads();  // drains B staging issued a full compute phase ago
        const int cur = kb & 1;
        bf16x8 a0n, a1n;
        if (kb < 3) {
            stageB(kb + 1, cur ^ 1);
            a0n = *(const bf16x8*)(ap + (kb + 1) * 64);
            a1n = *(const bf16x8*)(ap + (kb + 1) * 64 + 32);
        }
        const unsigned short* Blds = (const unsigned short*)(sm + cur * 8192);
#pragma unroll
        for (int ks = 0; ks < 2; ks++) {
            const bf16x8 a = ks ? a1 : a0;
#pragma unroll
            for (int t = 0; t < 4; t++) {
                const bf16x8 b = *(const bf16x8*)(Blds + bro[t][ks]);
                acc[t] = MFMA_BF16(a, b, acc[t]);
            }
        }
        if (kb < 3) {
            a0 = a0n;
            a1 = a1n;
        }
    }

    const float* bf_ = (const float*)biasv;
    const unsigned short* bh_ = (const unsigned short*)biasv;

    if (QKV && bn >= 512) {
        // V block: transpose via LDS, then write to TILED Vt[bh][kt][d][128k]
        __syncthreads();  // all waves done reading B buffers
        unsigned short* tr = (unsigned short*)sm;  // [64 d][72 pad] bf16
        const int lr = wv * 16 + quad * 4;
#pragma unroll
        for (int t = 0; t < 4; t++) {
            const int col = bn + t * 16 + m16;
            const float bv = f32 ? bf_[col] : bf2f(bh_[col]);
            uint2 w;
            w.x = pack_rh(acc[t][0] + bv, acc[t][1] + bv);
            w.y = pack_rh(acc[t][2] + bv, acc[t][3] + bv);
            *(uint2*)&tr[(t * 16 + m16) * 72 + lr] = w;
        }
        __syncthreads();
        // 4 threads per d-row, 16 elements (2 x uint4) each => full 64 covered
        const int d = tid >> 2;
        const int ch = (tid & 3) * 16;
        const uint4 o4a = *(const uint4*)&tr[d * 72 + ch];
        const uint4 o4b = *(const uint4*)&tr[d * 72 + ch + 8];
        const int hh = (bn - 512) >> 6;
        const int bb = bm >> 12, n0 = bm & 4095;
        const int nn = n0 + ch;                   // start n of this 16-chunk
        const int kt = nn >> 7, koff = nn & 127;  // k-tile, k within tile
        unsigned short* vdst =
            &Vt[(size_t)(((bb * 4 + hh) * 32 + kt) * 64 + d) * 128 + koff];
        *(uint4*)(vdst) = o4a;
        *(uint4*)(vdst + 8) = o4b;
        return;
    }

    const int row0 = bm + wv * 16 + quad * 4;
#pragma unroll
    for (int t = 0; t < 4; t++) {
        const int col = bn + t * 16 + m16;
        const float bv = f32 ? bf_[col] : bf2f(bh_[col]);
        float v[4];
#pragma unroll
        for (int r = 0; r < 4; r++) v[r] = acc[t][r] + bv;
        if (QKV) {
            const float sc = (col < 256) ? C1 : 1.0f;
#pragma unroll
            for (int r = 0; r < 4; r++)
                Cb[(size_t)(row0 + r) * 768 + col] = f2bf(v[r] * sc);
        } else {
            if (f32) {
#pragma unroll
                for (int r = 0; r < 4; r++) Cf[(size_t)(row0 + r) * Nout + col] = v[r];
            } else {
#pragma unroll
                for (int r = 0; r < 4; r++) Cb[(size_t)(row0 + r) * Nout + col] = f2bf(v[r]);
            }
        }
    }
}

// ---------------------------------------------------------------------------
// Flash attention v7 (VERIFIED 47.4-51.3 µs): barrier-free, wave-private
// slabs, tiled Vt, counted vmcnt, zero-shuffle PV + one-tile software-
// pipeline rotation (QK^T(t+1) before exp(t)/PV(t)).
// ---------------------------------------------------------------------------
#define ZERO_S(S)                                                     \
    do {                                                              \
        _Pragma("unroll") for (int mb = 0; mb < 2; mb++)              \
            _Pragma("unroll") for (int j = 0; j < 4; j++)             \
                S[mb][j] = (f32x4){0.f, 0.f, 0.f, 0.f};               \
    } while (0)

#define QKT(S, KBASE)                                                          \
    do {                                                                       \
        const unsigned short* Kb_ = (const unsigned short*)(KBASE);            \
        __builtin_amdgcn_s_setprio(1);                                         \
        _Pragma("unroll") for (int mb = 0; mb < 2; mb++)                       \
            _Pragma("unroll") for (int ks = 0; ks < 2; ks++) {                 \
                const bf16x8 ka_ = *(const bf16x8*)(Kb_ + kro[mb][ks]);        \
                _Pragma("unroll") for (int j = 0; j < 4; j++)                  \
                    S[mb][j] = MFMA_BF16(ka_, qf[j][ks], S[mb][j]);            \
            }                                                                  \
        __builtin_amdgcn_s_setprio(0);                                         \
    } while (0)

#define EXPP(S, PA)                                                            \
    do {                                                                       \
        _Pragma("unroll") for (int j = 0; j < 4; j++) {                        \
            const float e0 = exp2_hw(S[0][j][0]);                              \
            const float e1 = exp2_hw(S[0][j][1]);                              \
            const float e2 = exp2_hw(S[0][j][2]);                              \
            const float e3 = exp2_hw(S[0][j][3]);                              \
            const float e4 = exp2_hw(S[1][j][0]);                              \
            const float e5 = exp2_hw(S[1][j][1]);                              \
            const float e6 = exp2_hw(S[1][j][2]);                              \
            const float e7 = exp2_hw(S[1][j][3]);                              \
            uint4 pw_;                                                         \
            pw_.x = pack_rh(e0, e1);                                           \
            pw_.y = pack_rh(e2, e3);                                           \
            pw_.z = pack_rh(e4, e5);                                           \
            pw_.w = pack_rh(e6, e7);                                           \
            PA[j] = *(const bf16x8*)&pw_;                                      \
        }                                                                      \
    } while (0)

#define PVACC(PA, VBASE)                                                       \
    do {                                                                       \
        const unsigned short* Vb_ = (const unsigned short*)(VBASE);            \
        __builtin_amdgcn_s_setprio(1);                                         \
        _Pragma("unroll") for (int j = 0; j < 4; j++)                          \
            o1[j] = MFMA_BF16(PA[j], ones, o1[j]);                             \
        _Pragma("unroll") for (int t = 0; t < 4; t++) {                        \
            const uint2 va_ = *(const uint2*)(Vb_ + vroA[t]);                  \
            const uint2 vc_ = *(const uint2*)(Vb_ + (vroA[t] ^ 16));           \
            uint4 vv_;                                                         \
            vv_.x = va_.x;                                                     \
            vv_.y = va_.y;                                                     \
            vv_.z = vc_.x;                                                     \
            vv_.w = vc_.y;                                                     \
            const bf16x8 vb_ = *(const bf16x8*)&vv_;                           \
            _Pragma("unroll") for (int j = 0; j < 4; j++)                      \
                o[j][t] = MFMA_BF16(PA[j], vb_, o[j][t]);                      \
        }                                                                      \
        __builtin_amdgcn_s_setprio(0);                                         \
    } while (0)

#define GLK(DST)                                                               \
    {                                                                          \
        _Pragma("unroll") for (int i = 0; i < 4; i++)                          \
            gload16(kgn + kgo[i], (DST) + klo[i]);                             \
        kgn += 196608;                                                         \
    }
#define GLV(DST)                                                               \
    {                                                                          \
        _Pragma("unroll") for (int i = 0; i < 4; i++)                          \
            gload16(vgn + vgo[i], (DST) + vlo[i]);                             \
        vgn += 16384;                                                          \
    }

__global__ __launch_bounds__(256, 2) void attn_kernel(
    const unsigned short* __restrict__ qkv, const unsigned short* __restrict__ Vt,
    unsigned short* __restrict__ attn, int iters) {
    const int N = 4096, C3 = 768;
    __shared__ __align__(16) char sm[65536];  // [4 wv][2 buf][4KB K] | +32768 same for V

    const int tid = threadIdx.x;
    const int lane = tid & 63;
    const int wv = tid >> 6;
    const int m16 = lane & 15;
    const int quad = lane >> 4;

    const int bh = blockIdx.x & 7;  // XCD-locality: same bh -> same XCD
    const int qt = blockIdx.x >> 3;
    const int b = bh >> 2, h = bh & 3;

    // Q fragments (pre-scaled by C1 in gemm1): qf[j-block][kstep]
    bf16x8 qf[4][2];
#pragma unroll
    for (int j = 0; j < 4; j++)
#pragma unroll
        for (int ks = 0; ks < 2; ks++)
            qf[j][ks] = *(const bf16x8*)(qkv + ((size_t)b * N + qt * 64 + j * 16 + m16) * C3 +
                                         h * 64 + ks * 32 + quad * 8);

    // all-ones B operand (bf16 1.0 splat) for the l-row trick
    uint4 ones_u;
    ones_u.x = ones_u.y = ones_u.z = ones_u.w = 0x3F803F80u;
    const bf16x8 ones = *(const bf16x8*)&ones_u;

    // wave-private staging offsets (identical to v6).
    int kgo[4], vgo[4], klo[4], vlo[4];
#pragma unroll
    for (int i = 0; i < 4; i++) {
        const int c = i * 64 + lane;
        const int r = c >> 3, g = (c & 7) ^ (r & 7);
        kgo[i] = (wv * 32 + r) * 1536 + g * 16;
        klo[i] = c * 16;
        const int d = c >> 2, js = c & 3, jg = js ^ ((d >> 2) & 3);
        vgo[i] = d * 256 + wv * 64 + jg * 16;
        vlo[i] = c * 16;
    }
    int kro[2][2];
#pragma unroll
    for (int mb = 0; mb < 2; mb++)
#pragma unroll
        for (int ks = 0; ks < 2; ks++) {
            const int row = mb * 16 + m16;
            kro[mb][ks] = row * 64 + ((4 * ks + quad) ^ (m16 & 7)) * 8;
        }
    int vroA[4];
#pragma unroll
    for (int t = 0; t < 4; t++) {
        const int d = t * 16 + m16;
        const int c0 = (quad >> 1) ^ ((d >> 2) & 3);
        vroA[t] = d * 32 + c0 * 8 + (quad & 1) * 4;
    }

    char* Kreg0 = sm + wv * 8192;           // buf0; buf1 = +4096
    char* Vreg0 = sm + 32768 + wv * 8192;   // buf0; buf1 = +4096

    const char* kgp = (const char*)(qkv + (size_t)b * N * C3 + 256 + h * 64);
    const char* vgp = (const char*)(Vt + (size_t)bh * 262144);  // 32 tiles x 8192

    // prologue: tiles 0 and 1 fully issued (16 loads; qf's 8 loads precede)
#pragma unroll
    for (int i = 0; i < 4; i++) gload16(kgp + kgo[i], Kreg0 + klo[i]);
#pragma unroll
    for (int i = 0; i < 4; i++) gload16(vgp + vgo[i], Vreg0 + vlo[i]);
#pragma unroll
    for (int i = 0; i < 4; i++) gload16(kgp + 196608 + kgo[i], Kreg0 + 4096 + klo[i]);
#pragma unroll
    for (int i = 0; i < 4; i++) gload16(vgp + 16384 + vgo[i], Vreg0 + 4096 + vlo[i]);
    const char* kgn = kgp + 2 * 196608;  // next K to stage: tile 2
    const char* vgn = vgp + 2 * 16384;   // next V to stage: tile 2

    f32x4 o[4][4] = {};
    f32x4 o1[4] = {};  // l accumulator: o1[j][r] = l[q = j*16 + quad*4 + r]
    f32x4 sA[2][4], sB[2][4];
    bf16x8 pa[4];

    // preamble: S(0) (vmcnt(12) also drains the 8 qf loads + K(0))
    asm volatile("s_waitcnt vmcnt(12)" ::: "memory");
    ZERO_S(sA);
    QKT(sA, Kreg0);

    // 15 unrolled body-pairs = bodies 0..29 (tiles 0..29 consumed)
    for (int t2 = 0; t2 < 15; ++t2) {
        // body t = 2*t2 (even; cur=buf0): QK^T(t+1) || exp/PV(t)
        asm volatile("s_waitcnt vmcnt(4)" ::: "memory");  // V(t), K(t+1) landed
        GLK(Kreg0);                                       // K(t+2) -> buf0.K (K(t) free)
        ZERO_S(sB);
        QKT(sB, Kreg0 + 4096);                            // tile t+1 from buf1.K
        EXPP(sA, pa);                                     // independent of QKT above
        PVACC(pa, Vreg0);                                 // tile t from buf0.V
        asm volatile("s_waitcnt lgkmcnt(0)" ::: "memory");  // V reads retired
        GLV(Vreg0);                                       // V(t+2) -> buf0.V

        // body t+1 (odd; cur=buf1)
        asm volatile("s_waitcnt vmcnt(4)" ::: "memory");  // V(t+1), K(t+2) landed
        GLK(Kreg0 + 4096);                                // K(t+3) -> buf1.K
        ZERO_S(sA);
        QKT(sA, Kreg0);                                   // tile t+2 from buf0.K
        EXPP(sB, pa);
        PVACC(pa, Vreg0 + 4096);                          // tile t+1 from buf1.V
        asm volatile("s_waitcnt lgkmcnt(0)" ::: "memory");
        GLV(Vreg0 + 4096);                                // V(t+3) -> buf1.V
    }
    // body 30 (even; no prefetch): QK^T(31) || exp/PV(30)
    asm volatile("s_waitcnt vmcnt(4)" ::: "memory");      // V(30), K(31) landed
    ZERO_S(sB);
    QKT(sB, Kreg0 + 4096);
    EXPP(sA, pa);
    PVACC(pa, Vreg0);
    // body 31 (final): exp/PV(31)
    asm volatile("s_waitcnt vmcnt(0)" ::: "memory");      // V(31) landed
    EXPP(sB, pa);
    PVACC(pa, Vreg0 + 4096);

    // epilogue: cross-wave O/l reduction via LDS (first barrier of the kernel)
    __syncthreads();
    float* Ored = (float*)sm;            // [4 wv][16 q][64 d] slices per j
    float* lsum = (float*)(sm + 16384);  // [4 wv][64 q]
    if (m16 == 0) {
#pragma unroll
        for (int j = 0; j < 4; j++)
#pragma unroll
            for (int r = 0; r < 4; r++)
                lsum[wv * 64 + j * 16 + quad * 4 + r] = o1[j][r];
    }
    const int row = tid >> 4;
    const int col = (tid & 15) * 4;
#pragma unroll
    for (int j = 0; j < 4; j++) {
#pragma unroll
        for (int t = 0; t < 4; t++)
#pragma unroll
            for (int r = 0; r < 4; r++)
                Ored[(wv * 16 + quad * 4 + r) * 64 + t * 16 + m16] = o[j][t][r];
        __syncthreads();
        f32x4 sum = *(f32x4*)&Ored[row * 64 + col];
        sum += *(f32x4*)&Ored[1024 + row * 64 + col];
        sum += *(f32x4*)&Ored[2048 + row * 64 + col];
        sum += *(f32x4*)&Ored[3072 + row * 64 + col];
        const float lq = lsum[j * 16 + row] + lsum[64 + j * 16 + row] +
                         lsum[128 + j * 16 + row] + lsum[192 + j * 16 + row];
        const int n = qt * 64 + j * 16 + row;
        const float inv = 1.0f / lq;
        uint2 w;
        w.x = pack_rh(sum[0] * inv, sum[1] * inv);
        w.y = pack_rh(sum[2] * inv, sum[3] * inv);
        *(uint2*)&attn[((size_t)b * N + n) * 256 + h * 64 + col] = w;
        __syncthreads();
    }
}

// ---------------------------------------------------------------------------
extern "C" void kernel_launch(void* const* d_in, const int* in_sizes, int n_in,
                              void* d_out, int out_size, void* d_ws, size_t ws_size,
                              hipStream_t stream) {
    const int B = 2, N = 4096, H = 4;
    const int M = B * N;  // 8192

    // Workspace layout: qkv_ws at offset 0 (the r12/r14 attn-friendly base);
    // xb moved to the end. Pure address shuffle vs r13 — no logic change.
    char* wsb = (char*)d_ws;
    unsigned short* qkv_ws  = (unsigned short*)wsb;             // [8192][768] bf16
    unsigned short* Vt_ws   = qkv_ws + 6291456;                 // [8][32][64][128] tiled
    unsigned short* attn_ws = Vt_ws + 2097152;                  // [8192][256] bf16
    unsigned short* xb      = attn_ws + 2097152;                // [8192][256] bf16

    // 1) convert x only (weights consumed in-place by the gemms)
    convert_x_kernel<<<1024, 256, 0, stream>>>(d_in[0], xb);

    // 2) QKV projection: r8 double-buffered GEMM + fused weight conversion
    //    (Q pre-scaled by C1; V transposed via LDS to tiled Vt)
    gemm_kernel<true><<<dim3(M / 64, 768 / 64), 256, 0, stream>>>(
        xb, d_in[1], d_in[2], qkv_ws, nullptr, Vt_ws, 768);

    // 3) flash attention v7
    attn_kernel<<<512, 256, 0, stream>>>(qkv_ws, Vt_ws, attn_ws, 32);

    // 4) output projection (output dtype per own sniff)
    gemm_kernel<false><<<dim3(M / 64, 256 / 64), 256, 0, stream>>>(
        attn_ws, d_in[3], d_in[4], (unsigned short*)d_out, (float*)d_out, nullptr, 256);
}